// Round 2
// baseline (8305.513 us; speedup 1.0000x reference)
//
#include <hip/hip_runtime.h>
#include <hip/hip_bf16.h>

#define SEQ  2048
#define BAT  64
#define HID  128
#define LDSP 136   // padded LDS row length in bf16 elements (272 B, 16B-aligned, 2-way banks only)

typedef __bf16 bf16x8 __attribute__((ext_vector_type(8)));
typedef float  f32x4  __attribute__((ext_vector_type(4)));
typedef float  f32x8  __attribute__((ext_vector_type(8)));

__device__ __forceinline__ float sig_f(float x) {
    return __fdividef(1.0f, 1.0f + __expf(-x));
}
__device__ __forceinline__ float tanh_f(float x) {
    return 1.0f - __fdividef(2.0f, 1.0f + __expf(2.0f * x));
}
// convert 8 consecutive f32 to a bf16x8 MFMA fragment
__device__ __forceinline__ bf16x8 cvt8(const float* p) {
    bf16x8 r;
    #pragma unroll
    for (int i = 0; i < 8; ++i) r[i] = (__bf16)p[i];
    return r;
}
__device__ __forceinline__ bf16x8 cvt8v(f32x8 v) {
    bf16x8 r;
    #pragma unroll
    for (int i = 0; i < 8; ++i) r[i] = (__bf16)v[i];
    return r;
}

// 8 WGs: blockIdx = dir*4 + batch_tile. 512 thr = 8 waves; wave w owns gate dims [16w,16w+16).
// f32 I/O; matmuls in bf16 MFMA (f32 accumulate); c-recurrence kept in f32 registers.
__global__ __launch_bounds__(512, 2) void tlstm_bidir(
    const float* __restrict__ x,     const float* __restrict__ h0,
    const float* __restrict__ c0,    const float* __restrict__ dts,
    const float* __restrict__ Wih_f, const float* __restrict__ Whh_f,
    const float* __restrict__ bih_f, const float* __restrict__ bhh_f,
    const float* __restrict__ Wd_f,  const float* __restrict__ bd_f,
    const float* __restrict__ Wih_r, const float* __restrict__ Whh_r,
    const float* __restrict__ bih_r, const float* __restrict__ bhh_r,
    const float* __restrict__ Wd_r,  const float* __restrict__ bd_r,
    float* __restrict__ out)
{
    const int d    = blockIdx.x >> 2;          // 0 = forward, 1 = reverse
    const int m0   = (blockIdx.x & 3) * 16;    // batch row base
    const int tid  = threadIdx.x;
    const int w    = tid >> 6;                 // wave 0..7
    const int lane = tid & 63;
    const int nl   = lane & 15;                // n (col) within 16-wide tile
    const int q    = lane >> 4;                // quad 0..3
    const int j    = w * 16 + nl;              // hidden/gate dim owned by this lane

    const float* Wih = d ? Wih_r : Wih_f;
    const float* Whh = d ? Whh_r : Whh_f;
    const float* bih = d ? bih_r : bih_f;
    const float* bhh = d ? bhh_r : bhh_f;
    const float* Wd  = d ? Wd_r  : Wd_f;
    const float* bd  = d ? bd_r  : bd_f;

    __shared__ __align__(16) __bf16 h_a[2][16][LDSP];
    __shared__ __align__(16) __bf16 c_a[2][16][LDSP];

    // ---- resident weight B-fragments: B[k][n] = W[n][k]; lane holds n=nl(→j), k=kt*32+q*8..+8 ----
    bf16x8 whh_fr[4][4], wih_fr[4][4], wd_fr[4];
    #pragma unroll
    for (int g = 0; g < 4; ++g) {
        const int row = g * 128 + j;
        #pragma unroll
        for (int kt = 0; kt < 4; ++kt) {
            const int off = row * HID + kt * 32 + q * 8;
            wih_fr[g][kt] = cvt8(Wih + off);
            whh_fr[g][kt] = cvt8(Whh + off);
        }
    }
    #pragma unroll
    for (int kt = 0; kt < 4; ++kt)
        wd_fr[kt] = cvt8(Wd + j * HID + kt * 32 + q * 8);

    float bias_g[4];
    #pragma unroll
    for (int g = 0; g < 4; ++g)
        bias_g[g] = bih[g * 128 + j] + bhh[g * 128 + j];
    const float bias_d = bd[j];

    // ---- initial state: LDS buf 0 (bf16 A-layout) + f32 c in registers (C-layout) ----
    for (int e = tid; e < 16 * HID; e += 512) {
        const int m = e >> 7, k = e & 127;
        h_a[0][m][k] = (__bf16)h0[(d * BAT + m0 + m) * HID + k];
        c_a[0][m][k] = (__bf16)c0[(d * BAT + m0 + m) * HID + k];
    }
    float c_st[4];
    #pragma unroll
    for (int r = 0; r < 4; ++r)
        c_st[r] = c0[(d * BAT + m0 + q * 4 + r) * HID + j];
    __syncthreads();

    // ---- x prefetch (f32) for first step ----
    f32x8 xpref[4];
    {
        const int t0 = d ? (SEQ - 1) : 0;
        #pragma unroll
        for (int kt = 0; kt < 4; ++kt)
            xpref[kt] = *reinterpret_cast<const f32x8*>(
                x + ((t0 * BAT + m0 + nl) * HID + kt * 32 + q * 8));
    }

    for (int ts = 0; ts < SEQ; ++ts) {
        const int t = d ? (SEQ - 1 - ts) : ts;
        const int p = ts & 1;

        // convert prefetched x to bf16 A-frags (loads are a full step old -> no stall),
        // then issue next step's prefetch
        bf16x8 xcur[4];
        #pragma unroll
        for (int kt = 0; kt < 4; ++kt) xcur[kt] = cvt8v(xpref[kt]);
        {
            int tn = d ? (t - 1) : (t + 1);
            tn = tn < 0 ? 0 : (tn >= SEQ ? SEQ - 1 : tn);
            #pragma unroll
            for (int kt = 0; kt < 4; ++kt)
                xpref[kt] = *reinterpret_cast<const f32x8*>(
                    x + ((tn * BAT + m0 + nl) * HID + kt * 32 + q * 8));
        }

        // per-row 1/ln(e+dt); rows b = m0 + q*4 + r, dts is [B][S]
        float ilog[4];
        #pragma unroll
        for (int r = 0; r < 4; ++r) {
            const float dtv = dts[(m0 + q * 4 + r) * SEQ + t];
            ilog[r] = __fdividef(1.0f, __logf(2.718281828459045f + dtv));
        }

        f32x4 ai  = {bias_g[0], bias_g[0], bias_g[0], bias_g[0]};
        f32x4 af  = {bias_g[1], bias_g[1], bias_g[1], bias_g[1]};
        f32x4 ag  = {bias_g[2], bias_g[2], bias_g[2], bias_g[2]};
        f32x4 ao  = {bias_g[3], bias_g[3], bias_g[3], bias_g[3]};
        f32x4 acs = {bias_d, bias_d, bias_d, bias_d};

        #pragma unroll
        for (int kt = 0; kt < 4; ++kt) {
            const bf16x8 hfr = *reinterpret_cast<const bf16x8*>(&h_a[p][nl][kt * 32 + q * 8]);
            ai = __builtin_amdgcn_mfma_f32_16x16x32_bf16(hfr, whh_fr[0][kt], ai, 0, 0, 0);
            af = __builtin_amdgcn_mfma_f32_16x16x32_bf16(hfr, whh_fr[1][kt], af, 0, 0, 0);
            ag = __builtin_amdgcn_mfma_f32_16x16x32_bf16(hfr, whh_fr[2][kt], ag, 0, 0, 0);
            ao = __builtin_amdgcn_mfma_f32_16x16x32_bf16(hfr, whh_fr[3][kt], ao, 0, 0, 0);
            ai = __builtin_amdgcn_mfma_f32_16x16x32_bf16(xcur[kt], wih_fr[0][kt], ai, 0, 0, 0);
            af = __builtin_amdgcn_mfma_f32_16x16x32_bf16(xcur[kt], wih_fr[1][kt], af, 0, 0, 0);
            ag = __builtin_amdgcn_mfma_f32_16x16x32_bf16(xcur[kt], wih_fr[2][kt], ag, 0, 0, 0);
            ao = __builtin_amdgcn_mfma_f32_16x16x32_bf16(xcur[kt], wih_fr[3][kt], ao, 0, 0, 0);
            const bf16x8 cfr = *reinterpret_cast<const bf16x8*>(&c_a[p][nl][kt * 32 + q * 8]);
            acs = __builtin_amdgcn_mfma_f32_16x16x32_bf16(cfr, wd_fr[kt], acs, 0, 0, 0);
        }

        // ---- epilogue: C/D layout row = q*4+r (batch), col = nl (-> gate dim j) ----
        const int pn = p ^ 1;
        #pragma unroll
        for (int r = 0; r < 4; ++r) {
            const float cs   = tanh_f(acs[r]);
            const float cadj = c_st[r] - cs + cs * ilog[r];
            const float gi   = sig_f(ai[r]);
            const float gf   = sig_f(af[r]);
            const float gg   = tanh_f(ag[r]);
            const float go   = sig_f(ao[r]);
            const float cn   = gf * cadj + gi * gg;
            const float hn   = go * tanh_f(cn);
            c_st[r] = cn;
            h_a[pn][q * 4 + r][j] = (__bf16)hn;
            c_a[pn][q * 4 + r][j] = (__bf16)cn;
            out[(t * BAT + m0 + q * 4 + r) * 256 + d * 128 + j] = hn;
        }

        // raw barrier: order LDS ops (lgkmcnt) but DO NOT drain vmcnt —
        // keeps x prefetch + out stores in flight across the step boundary.
        asm volatile("s_waitcnt lgkmcnt(0)\n\ts_barrier" ::: "memory");
    }
}

extern "C" void kernel_launch(void* const* d_in, const int* in_sizes, int n_in,
                              void* d_out, int out_size, void* d_ws, size_t ws_size,
                              hipStream_t stream) {
    const float* x     = (const float*)d_in[0];
    const float* h0    = (const float*)d_in[1];
    const float* c0    = (const float*)d_in[2];
    const float* dts   = (const float*)d_in[3];
    const float* Wih_f = (const float*)d_in[4];
    const float* Whh_f = (const float*)d_in[5];
    const float* bih_f = (const float*)d_in[6];
    const float* bhh_f = (const float*)d_in[7];
    const float* Wd_f  = (const float*)d_in[8];
    const float* bd_f  = (const float*)d_in[9];
    const float* Wih_r = (const float*)d_in[10];
    const float* Whh_r = (const float*)d_in[11];
    const float* bih_r = (const float*)d_in[12];
    const float* bhh_r = (const float*)d_in[13];
    const float* Wd_r  = (const float*)d_in[14];
    const float* bd_r  = (const float*)d_in[15];
    float* out = (float*)d_out;

    tlstm_bidir<<<8, 512, 0, stream>>>(x, h0, c0, dts,
                                       Wih_f, Whh_f, bih_f, bhh_f, Wd_f, bd_f,
                                       Wih_r, Whh_r, bih_r, bhh_r, Wd_r, bd_r,
                                       out);
}

// Round 4
// 4571.518 us; speedup vs baseline: 1.8168x; 1.8168x over previous
//
#include <hip/hip_runtime.h>
#include <hip/hip_bf16.h>

#define SEQ  2048
#define BAT  64
#define HID  128
#define LDSP 136   // padded LDS row: 272 B -> 4-bank shift/row, b128 reads spread all 32 banks

// workspace layout (needs ~36 MiB)
#define XB_OFF  (1u << 20)            // bf16 x, 32 MiB, 1 MiB slack below for reverse-dir overrun
#define IL_OFF  (35u << 20)           // f32 ilogm1[t][b], 512 KiB, slack both sides

typedef __bf16 bf16x8 __attribute__((ext_vector_type(8)));
typedef float  f32x4  __attribute__((ext_vector_type(4)));

#define MFMA(a,b,c) __builtin_amdgcn_mfma_f32_16x16x32_bf16((a),(b),(c),0,0,0)

__device__ __forceinline__ float sig_f(float x) {
    return __fdividef(1.0f, 1.0f + __expf(-x));
}
__device__ __forceinline__ float tanh_f(float x) {
    return 1.0f - __fdividef(2.0f, 1.0f + __expf(2.0f * x));
}
__device__ __forceinline__ bf16x8 cvt8(const float* p) {
    bf16x8 r;
    #pragma unroll
    for (int i = 0; i < 8; ++i) r[i] = (__bf16)p[i];
    return r;
}

// ---- pre-kernel 1: x f32 -> bf16, same [S][B][I] layout ----
__global__ void cvt_x_kernel(const float* __restrict__ x, __bf16* __restrict__ xb) {
    const int i = (blockIdx.x * 256 + threadIdx.x) * 4;   // 16777216 elems / 4 per thread
    const float4 v = *reinterpret_cast<const float4*>(x + i);
    __bf16 o[4];
    o[0] = (__bf16)v.x; o[1] = (__bf16)v.y; o[2] = (__bf16)v.z; o[3] = (__bf16)v.w;
    *reinterpret_cast<uint2*>(xb + i) = *reinterpret_cast<const uint2*>(o);
}

// ---- pre-kernel 2: ilogm1[t][b] = 1/ln(e + dts[b][t]) - 1 ----
__global__ void prep_ilog_kernel(const float* __restrict__ dts, float* __restrict__ il) {
    const int idx = blockIdx.x * 256 + threadIdx.x;       // 131072 total, b-major read
    const int b = idx >> 11, t = idx & 2047;
    const float l = __logf(2.718281828459045f + dts[idx]);
    il[t * BAT + b] = __fdividef(1.0f, l) - 1.0f;
}

// 8 WGs: blockIdx = dir*4 + batch_tile. 512 thr = 8 waves; wave w owns gate dims [16w,16w+16).
__global__ __launch_bounds__(512, 2) void tlstm_main(
    const __bf16* __restrict__ xb,   const float* __restrict__ ilg,
    const float* __restrict__ h0,    const float* __restrict__ c0,
    const float* __restrict__ Wih_f, const float* __restrict__ Whh_f,
    const float* __restrict__ bih_f, const float* __restrict__ bhh_f,
    const float* __restrict__ Wd_f,  const float* __restrict__ bd_f,
    const float* __restrict__ Wih_r, const float* __restrict__ Whh_r,
    const float* __restrict__ bih_r, const float* __restrict__ bhh_r,
    const float* __restrict__ Wd_r,  const float* __restrict__ bd_r,
    float* __restrict__ out)
{
    const int d    = blockIdx.x >> 2;
    const int m0   = (blockIdx.x & 3) * 16;
    const int tid  = threadIdx.x;
    const int w    = tid >> 6;
    const int lane = tid & 63;
    const int nl   = lane & 15;
    const int q    = lane >> 4;
    const int j    = w * 16 + nl;

    const float* Wih = d ? Wih_r : Wih_f;
    const float* Whh = d ? Whh_r : Whh_f;
    const float* bih = d ? bih_r : bih_f;
    const float* bhh = d ? bhh_r : bhh_f;
    const float* Wd  = d ? Wd_r  : Wd_f;
    const float* bd  = d ? bd_r  : bd_f;

    __shared__ __align__(16) __bf16 h_a[2][16][LDSP];
    __shared__ __align__(16) __bf16 c_a[2][16][LDSP];

    // resident weight B-frags: B[k][n] = W[n][k]; lane: n=nl(->j), k = kt*32 + q*8 ..+8
    bf16x8 whh_fr[4][4], wih_fr[4][4], wd_fr[4];
    #pragma unroll
    for (int g = 0; g < 4; ++g) {
        const int row = g * 128 + j;
        #pragma unroll
        for (int kt = 0; kt < 4; ++kt) {
            const int off = row * HID + kt * 32 + q * 8;
            wih_fr[g][kt] = cvt8(Wih + off);
            whh_fr[g][kt] = cvt8(Whh + off);
        }
    }
    #pragma unroll
    for (int kt = 0; kt < 4; ++kt)
        wd_fr[kt] = cvt8(Wd + j * HID + kt * 32 + q * 8);

    float bias_g[4];
    #pragma unroll
    for (int g = 0; g < 4; ++g)
        bias_g[g] = bih[g * 128 + j] + bhh[g * 128 + j];
    const float bias_d = bd[j];

    // initial state
    for (int e = tid; e < 16 * HID; e += 512) {
        const int m = e >> 7, k = e & 127;
        h_a[0][m][k] = (__bf16)h0[(d * BAT + m0 + m) * HID + k];
        c_a[0][m][k] = (__bf16)c0[(d * BAT + m0 + m) * HID + k];
    }
    float c_st[4];
    #pragma unroll
    for (int r = 0; r < 4; ++r)
        c_st[r] = c0[(d * BAT + m0 + q * 4 + r) * HID + j];
    __syncthreads();

    // running pointers
    const int t0     = d ? (SEQ - 1) : 0;
    const int tstep  = d ? -1 : 1;
    const int xstride = tstep * BAT * HID;   // elements
    const int istride = tstep * BAT;
    const int ostride = tstep * BAT * 256;

    const __bf16* xp = xb + (size_t)(t0 * BAT + m0 + nl) * HID + q * 8;
    const float*  ip = ilg + (size_t)t0 * BAT + m0 + q * 4;
    float*        op = out + (size_t)(t0 * BAT + m0 + q * 4) * 256 + d * 128 + j;

    // ---- pipeline prologue ----
    bf16x8 xfrA[4], xfrB[4];
    float  ilA[4], ilB[4];
    f32x4  xaccA[4], xaccB[4];

    #pragma unroll
    for (int kt = 0; kt < 4; ++kt)
        xfrA[kt] = *reinterpret_cast<const bf16x8*>(xp + kt * 32);   // x[step 0]
    #pragma unroll
    for (int r = 0; r < 4; ++r) ilA[r] = ip[r];                       // il[step 0]
    #pragma unroll
    for (int g = 0; g < 4; ++g)
        xaccA[g] = f32x4{bias_g[g], bias_g[g], bias_g[g], bias_g[g]};
    #pragma unroll
    for (int kt = 0; kt < 4; ++kt) {
        xaccA[0] = MFMA(xfrA[kt], wih_fr[0][kt], xaccA[0]);
        xaccA[1] = MFMA(xfrA[kt], wih_fr[1][kt], xaccA[1]);
        xaccA[2] = MFMA(xfrA[kt], wih_fr[2][kt], xaccA[2]);
        xaccA[3] = MFMA(xfrA[kt], wih_fr[3][kt], xaccA[3]);
    }
    xp += xstride; ip += istride;
    #pragma unroll
    for (int kt = 0; kt < 4; ++kt)
        xfrB[kt] = *reinterpret_cast<const bf16x8*>(xp + kt * 32);   // x[step 1]
    #pragma unroll
    for (int r = 0; r < 4; ++r) ilB[r] = ip[r];                       // il[step 1]

    // one LSTM step; accIn = this step's x-gates(+bias); xfrIn = next step's x frags;
    // xfrLd / ilBuf get refilled with step+2 data; accOut = next step's x-gates.
    auto lstm_step = [&](int p, f32x4 (&accIn)[4], f32x4 (&accOut)[4],
                         bf16x8 (&xfrIn)[4], bf16x8 (&xfrLd)[4],
                         float (&ilBuf)[4]) __attribute__((always_inline)) {
        f32x4 ai = accIn[0], af = accIn[1], ag = accIn[2], ao = accIn[3];
        f32x4 acs = f32x4{bias_d, bias_d, bias_d, bias_d};
        #pragma unroll
        for (int kt = 0; kt < 4; ++kt) {
            const bf16x8 hfr = *reinterpret_cast<const bf16x8*>(&h_a[p][nl][kt * 32 + q * 8]);
            ai  = MFMA(hfr, whh_fr[0][kt], ai);
            af  = MFMA(hfr, whh_fr[1][kt], af);
            ag  = MFMA(hfr, whh_fr[2][kt], ag);
            ao  = MFMA(hfr, whh_fr[3][kt], ao);
            const bf16x8 cfr = *reinterpret_cast<const bf16x8*>(&c_a[p][nl][kt * 32 + q * 8]);
            acs = MFMA(cfr, wd_fr[kt], acs);
        }

        // prefetch step+2 (consumed two steps from now -> latency fully hidden)
        xp += xstride; ip += istride;
        #pragma unroll
        for (int kt = 0; kt < 4; ++kt)
            xfrLd[kt] = *reinterpret_cast<const bf16x8*>(xp + kt * 32);
        float il2[4];
        #pragma unroll
        for (int r = 0; r < 4; ++r) il2[r] = ip[r];

        // epilogue: C/D layout row = q*4+r (batch), col = j
        const int pn = p ^ 1;
        #pragma unroll
        for (int r = 0; r < 4; ++r) {
            const float cs   = tanh_f(acs[r]);
            const float cadj = fmaf(cs, ilBuf[r], c_st[r]);   // c + cs*(ilog-1)
            const float gi   = sig_f(ai[r]);
            const float gf   = sig_f(af[r]);
            const float gg   = tanh_f(ag[r]);
            const float go   = sig_f(ao[r]);
            const float cn   = gf * cadj + gi * gg;
            const float hn   = go * tanh_f(cn);
            c_st[r] = cn;
            h_a[pn][q * 4 + r][j] = (__bf16)hn;
            c_a[pn][q * 4 + r][j] = (__bf16)cn;
            op[r * 256] = hn;
        }
        op += ostride;
        #pragma unroll
        for (int r = 0; r < 4; ++r) ilBuf[r] = il2[r];

        // next step's x-gate contributions (overlaps the trans-stall window)
        #pragma unroll
        for (int g = 0; g < 4; ++g)
            accOut[g] = f32x4{bias_g[g], bias_g[g], bias_g[g], bias_g[g]};
        #pragma unroll
        for (int kt = 0; kt < 4; ++kt) {
            accOut[0] = MFMA(xfrIn[kt], wih_fr[0][kt], accOut[0]);
            accOut[1] = MFMA(xfrIn[kt], wih_fr[1][kt], accOut[1]);
            accOut[2] = MFMA(xfrIn[kt], wih_fr[2][kt], accOut[2]);
            accOut[3] = MFMA(xfrIn[kt], wih_fr[3][kt], accOut[3]);
        }

        // order LDS ops only; keep global loads/stores in flight across the barrier
        asm volatile("s_waitcnt lgkmcnt(0)\n\ts_barrier" ::: "memory");
    };

    for (int ts = 0; ts < SEQ; ts += 2) {
        lstm_step(0, xaccA, xaccB, xfrB, xfrA, ilA);
        lstm_step(1, xaccB, xaccA, xfrA, xfrB, ilB);
    }
}

extern "C" void kernel_launch(void* const* d_in, const int* in_sizes, int n_in,
                              void* d_out, int out_size, void* d_ws, size_t ws_size,
                              hipStream_t stream) {
    const float* x     = (const float*)d_in[0];
    const float* h0    = (const float*)d_in[1];
    const float* c0    = (const float*)d_in[2];
    const float* dts   = (const float*)d_in[3];
    const float* Wih_f = (const float*)d_in[4];
    const float* Whh_f = (const float*)d_in[5];
    const float* bih_f = (const float*)d_in[6];
    const float* bhh_f = (const float*)d_in[7];
    const float* Wd_f  = (const float*)d_in[8];
    const float* bd_f  = (const float*)d_in[9];
    const float* Wih_r = (const float*)d_in[10];
    const float* Whh_r = (const float*)d_in[11];
    const float* bih_r = (const float*)d_in[12];
    const float* bhh_r = (const float*)d_in[13];
    const float* Wd_r  = (const float*)d_in[14];
    const float* bd_r  = (const float*)d_in[15];
    float* out = (float*)d_out;

    __bf16* xbuf = (__bf16*)((char*)d_ws + XB_OFF);
    float*  il   = (float*)((char*)d_ws + IL_OFF);

    cvt_x_kernel<<<16384, 256, 0, stream>>>(x, xbuf);         // 16.8M elems / 4 per thread
    prep_ilog_kernel<<<512, 256, 0, stream>>>(dts, il);       // 131072 elems

    tlstm_main<<<8, 512, 0, stream>>>(xbuf, il, h0, c0,
                                      Wih_f, Whh_f, bih_f, bhh_f, Wd_f, bd_f,
                                      Wih_r, Whh_r, bih_r, bhh_r, Wd_r, bd_r,
                                      out);
}

// Round 5
// 2045.401 us; speedup vs baseline: 4.0606x; 2.2350x over previous
//
#include <hip/hip_runtime.h>
#include <hip/hip_bf16.h>

#define SEQ  2048
#define BAT  64
#define HID  128
#define LDSP 136   // padded LDS row: 272 B

// workspace layout (needs ~36 MiB, proven available in Round 4)
#define XB_OFF  (1u << 20)            // bf16 x, 32 MiB
#define IL_OFF  (35u << 20)           // f32 ilogm1[t][b], 512 KiB

typedef __bf16 bf16x8 __attribute__((ext_vector_type(8)));
typedef float  f32x4  __attribute__((ext_vector_type(4)));

#define MFMA(a,b,c) __builtin_amdgcn_mfma_f32_16x16x32_bf16((a),(b),(c),0,0,0)

__device__ __forceinline__ float sig_f(float x) {
    return __fdividef(1.0f, 1.0f + __expf(-x));
}
__device__ __forceinline__ float tanh_f(float x) {
    return 1.0f - __fdividef(2.0f, 1.0f + __expf(2.0f * x));
}
__device__ __forceinline__ bf16x8 cvt8(const float* p) {
    bf16x8 r;
    #pragma unroll
    for (int i = 0; i < 8; ++i) r[i] = (__bf16)p[i];
    return r;
}

// ---- pre-kernel 1: x f32 -> bf16, same [S][B][I] layout ----
__global__ void cvt_x_kernel(const float* __restrict__ x, __bf16* __restrict__ xb) {
    const int i = (blockIdx.x * 256 + threadIdx.x) * 4;
    const float4 v = *reinterpret_cast<const float4*>(x + i);
    __bf16 o[4];
    o[0] = (__bf16)v.x; o[1] = (__bf16)v.y; o[2] = (__bf16)v.z; o[3] = (__bf16)v.w;
    *reinterpret_cast<uint2*>(xb + i) = *reinterpret_cast<const uint2*>(o);
}

// ---- pre-kernel 2: ilogm1[t][b] = 1/ln(e + dts[b][t]) - 1 ----
__global__ void prep_ilog_kernel(const float* __restrict__ dts, float* __restrict__ il) {
    const int idx = blockIdx.x * 256 + threadIdx.x;
    const int b = idx >> 11, t = idx & 2047;
    const float l = __logf(2.718281828459045f + dts[idx]);
    il[t * BAT + b] = __fdividef(1.0f, l) - 1.0f;
}

// 32 WGs: blockIdx = dir*16 + batch_tile; each WG owns 4 chains (batch rows b0..b0+3).
// M=16 MFMA tiles carry the 4 real rows at A-rows/C-rows {0,4,8,12} (C reg r=0, row q*4).
// Pad rows hold garbage that provably never contaminates valid rows (D row m sums only A row m;
// pad LDS rows are never written by the epilogue and only feed pad C rows).
// 512 thr = 8 waves; wave w owns gate dims j in [16w, 16w+16).
__global__ __launch_bounds__(512, 2) void tlstm_main(
    const __bf16* __restrict__ xb,   const float* __restrict__ ilg,
    const float* __restrict__ h0,    const float* __restrict__ c0,
    const float* __restrict__ Wih_f, const float* __restrict__ Whh_f,
    const float* __restrict__ bih_f, const float* __restrict__ bhh_f,
    const float* __restrict__ Wd_f,  const float* __restrict__ bd_f,
    const float* __restrict__ Wih_r, const float* __restrict__ Whh_r,
    const float* __restrict__ bih_r, const float* __restrict__ bhh_r,
    const float* __restrict__ Wd_r,  const float* __restrict__ bd_r,
    float* __restrict__ out)
{
    const int d    = blockIdx.x >> 4;
    const int b0   = (blockIdx.x & 15) * 4;    // 4 chains per WG
    const int tid  = threadIdx.x;
    const int w    = tid >> 6;
    const int lane = tid & 63;
    const int nl   = lane & 15;
    const int q    = lane >> 4;
    const int j    = w * 16 + nl;

    const float* Wih = d ? Wih_r : Wih_f;
    const float* Whh = d ? Whh_r : Whh_f;
    const float* bih = d ? bih_r : bih_f;
    const float* bhh = d ? bhh_r : bhh_f;
    const float* Wd  = d ? Wd_r  : Wd_f;
    const float* bd  = d ? bd_r  : bd_f;

    __shared__ __align__(16) __bf16 h_a[2][16][LDSP];
    __shared__ __align__(16) __bf16 c_a[2][16][LDSP];

    // resident weight B-frags: B[k][n] = W[n][k]; lane: n=nl(->j), k = kt*32 + q*8 ..+8
    bf16x8 whh_fr[4][4], wih_fr[4][4], wd_fr[4];
    #pragma unroll
    for (int g = 0; g < 4; ++g) {
        const int row = g * 128 + j;
        #pragma unroll
        for (int kt = 0; kt < 4; ++kt) {
            const int off = row * HID + kt * 32 + q * 8;
            wih_fr[g][kt] = cvt8(Wih + off);
            whh_fr[g][kt] = cvt8(Whh + off);
        }
    }
    #pragma unroll
    for (int kt = 0; kt < 4; ++kt)
        wd_fr[kt] = cvt8(Wd + j * HID + kt * 32 + q * 8);

    float bias_g[4];
    #pragma unroll
    for (int g = 0; g < 4; ++g)
        bias_g[g] = bih[g * 128 + j] + bhh[g * 128 + j];
    const float bias_d = bd[j];

    // initial state: valid rows {0,4,8,12} only (4 chains); pads left as-is
    for (int e = tid; e < 4 * HID; e += 512) {
        const int ci = e >> 7, k = e & 127;
        h_a[0][ci * 4][k] = (__bf16)h0[(d * BAT + b0 + ci) * HID + k];
        c_a[0][ci * 4][k] = (__bf16)c0[(d * BAT + b0 + ci) * HID + k];
    }
    float c_st = c0[(d * BAT + b0 + q) * HID + j];   // lane's chain = q (C row q*4, reg 0)
    __syncthreads();

    // running pointers
    const int t0      = d ? (SEQ - 1) : 0;
    const int tstep   = d ? -1 : 1;
    const int xstride = tstep * BAT * HID;
    const int istride = tstep * BAT;
    const int ostride = tstep * BAT * 256;

    // A-row nl -> chain nl>>2 (pad lanes duplicate their quad's chain; same cache line)
    const __bf16* xp = xb + (size_t)(t0 * BAT + b0 + (nl >> 2)) * HID + q * 8;
    const float*  ip = ilg + (size_t)t0 * BAT + b0 + q;
    float*        op = out + (size_t)(t0 * BAT + b0 + q) * 256 + d * 128 + j;

    // ---- pipeline prologue ----
    bf16x8 xfrA[4], xfrB[4];
    float  ilA, ilB;
    f32x4  xaccA[4], xaccB[4];

    #pragma unroll
    for (int kt = 0; kt < 4; ++kt)
        xfrA[kt] = *reinterpret_cast<const bf16x8*>(xp + kt * 32);   // x[step 0]
    ilA = *ip;
    #pragma unroll
    for (int g = 0; g < 4; ++g)
        xaccA[g] = f32x4{bias_g[g], bias_g[g], bias_g[g], bias_g[g]};
    #pragma unroll
    for (int kt = 0; kt < 4; ++kt) {
        xaccA[0] = MFMA(xfrA[kt], wih_fr[0][kt], xaccA[0]);
        xaccA[1] = MFMA(xfrA[kt], wih_fr[1][kt], xaccA[1]);
        xaccA[2] = MFMA(xfrA[kt], wih_fr[2][kt], xaccA[2]);
        xaccA[3] = MFMA(xfrA[kt], wih_fr[3][kt], xaccA[3]);
    }
    xp += xstride; ip += istride;
    #pragma unroll
    for (int kt = 0; kt < 4; ++kt)
        xfrB[kt] = *reinterpret_cast<const bf16x8*>(xp + kt * 32);   // x[step 1]
    ilB = *ip;

    auto lstm_step = [&](int p, f32x4 (&accIn)[4], f32x4 (&accOut)[4],
                         bf16x8 (&xfrIn)[4], bf16x8 (&xfrLd)[4],
                         float& ilBuf) __attribute__((always_inline)) {
        f32x4 ai = accIn[0], af = accIn[1], ag = accIn[2], ao = accIn[3];
        f32x4 acs = f32x4{bias_d, bias_d, bias_d, bias_d};
        #pragma unroll
        for (int kt = 0; kt < 4; ++kt) {
            const bf16x8 hfr = *reinterpret_cast<const bf16x8*>(&h_a[p][nl][kt * 32 + q * 8]);
            ai  = MFMA(hfr, whh_fr[0][kt], ai);
            af  = MFMA(hfr, whh_fr[1][kt], af);
            ag  = MFMA(hfr, whh_fr[2][kt], ag);
            ao  = MFMA(hfr, whh_fr[3][kt], ao);
            const bf16x8 cfr = *reinterpret_cast<const bf16x8*>(&c_a[p][nl][kt * 32 + q * 8]);
            acs = MFMA(cfr, wd_fr[kt], acs);
        }

        // prefetch step+2 (consumed two steps out -> latency fully hidden)
        xp += xstride; ip += istride;
        #pragma unroll
        for (int kt = 0; kt < 4; ++kt)
            xfrLd[kt] = *reinterpret_cast<const bf16x8*>(xp + kt * 32);
        const float il2 = *ip;

        // epilogue: single valid cell per lane — C reg 0 = row q*4 (chain q), col j
        const int pn = p ^ 1;
        {
            const float cs   = tanh_f(acs[0]);
            const float cadj = fmaf(cs, ilBuf, c_st);   // c + cs*(ilog-1)
            const float gi   = sig_f(ai[0]);
            const float gf   = sig_f(af[0]);
            const float gg   = tanh_f(ag[0]);
            const float go   = sig_f(ao[0]);
            const float cn   = gf * cadj + gi * gg;
            const float hn   = go * tanh_f(cn);
            c_st = cn;
            h_a[pn][q * 4][j] = (__bf16)hn;
            c_a[pn][q * 4][j] = (__bf16)cn;
            *op = hn;
        }
        op += ostride;
        ilBuf = il2;

        // next step's x-gate contributions (overlaps the trans-stall window)
        #pragma unroll
        for (int g = 0; g < 4; ++g)
            accOut[g] = f32x4{bias_g[g], bias_g[g], bias_g[g], bias_g[g]};
        #pragma unroll
        for (int kt = 0; kt < 4; ++kt) {
            accOut[0] = MFMA(xfrIn[kt], wih_fr[0][kt], accOut[0]);
            accOut[1] = MFMA(xfrIn[kt], wih_fr[1][kt], accOut[1]);
            accOut[2] = MFMA(xfrIn[kt], wih_fr[2][kt], accOut[2]);
            accOut[3] = MFMA(xfrIn[kt], wih_fr[3][kt], accOut[3]);
        }

        // order LDS ops only; keep global loads/stores in flight across the barrier
        asm volatile("s_waitcnt lgkmcnt(0)\n\ts_barrier" ::: "memory");
    };

    for (int ts = 0; ts < SEQ; ts += 2) {
        lstm_step(0, xaccA, xaccB, xfrB, xfrA, ilA);
        lstm_step(1, xaccB, xaccA, xfrA, xfrB, ilB);
    }
}

extern "C" void kernel_launch(void* const* d_in, const int* in_sizes, int n_in,
                              void* d_out, int out_size, void* d_ws, size_t ws_size,
                              hipStream_t stream) {
    const float* x     = (const float*)d_in[0];
    const float* h0    = (const float*)d_in[1];
    const float* c0    = (const float*)d_in[2];
    const float* dts   = (const float*)d_in[3];
    const float* Wih_f = (const float*)d_in[4];
    const float* Whh_f = (const float*)d_in[5];
    const float* bih_f = (const float*)d_in[6];
    const float* bhh_f = (const float*)d_in[7];
    const float* Wd_f  = (const float*)d_in[8];
    const float* bd_f  = (const float*)d_in[9];
    const float* Wih_r = (const float*)d_in[10];
    const float* Whh_r = (const float*)d_in[11];
    const float* bih_r = (const float*)d_in[12];
    const float* bhh_r = (const float*)d_in[13];
    const float* Wd_r  = (const float*)d_in[14];
    const float* bd_r  = (const float*)d_in[15];
    float* out = (float*)d_out;

    __bf16* xbuf = (__bf16*)((char*)d_ws + XB_OFF);
    float*  il   = (float*)((char*)d_ws + IL_OFF);

    cvt_x_kernel<<<16384, 256, 0, stream>>>(x, xbuf);
    prep_ilog_kernel<<<512, 256, 0, stream>>>(dts, il);

    tlstm_main<<<32, 512, 0, stream>>>(xbuf, il, h0, c0,
                                       Wih_f, Whh_f, bih_f, bhh_f, Wd_f, bd_f,
                                       Wih_r, Whh_r, bih_r, bhh_r, Wd_r, bd_r,
                                       out);
}